// Round 1
// baseline (449.224 us; speedup 1.0000x reference)
//
#include <hip/hip_runtime.h>

#define N_NODES 16384
#define N_EDGES 524288
#define CH 128

// ---------------- histogram of dst (deg counts, duplicates included) --------
__global__ void hist_kernel(const int* __restrict__ dst, int* __restrict__ count) {
    int e = blockIdx.x * 256 + threadIdx.x;
    if (e < N_EDGES) atomicAdd(&count[dst[e]], 1);
}

// ---------------- exclusive scan of 16384 counts -> indptr ------------------
__global__ void scan_kernel(const int* __restrict__ count, int* __restrict__ indptr) {
    __shared__ int part[256];
    int t = threadIdx.x;
    int base = t * 64;
    int local[64];
    int s = 0;
#pragma unroll
    for (int i = 0; i < 64; ++i) { local[i] = s; s += count[base + i]; }
    part[t] = s;
    __syncthreads();
    for (int off = 1; off < 256; off <<= 1) {
        int v = (t >= off) ? part[t - off] : 0;
        __syncthreads();
        part[t] += v;
        __syncthreads();
    }
    int prefix = (t == 0) ? 0 : part[t - 1];
#pragma unroll
    for (int i = 0; i < 64; ++i) indptr[base + i] = prefix + local[i];
    if (t == 255) indptr[N_NODES] = part[255];
}

// ---------------- dinv = rsqrt(deg), deg = count + 1 (self loop) ------------
__global__ void dinv_kernel(const int* __restrict__ count, float* __restrict__ dinv) {
    int n = blockIdx.x * 256 + threadIdx.x;
    if (n < N_NODES) dinv[n] = rsqrtf((float)(count[n] + 1));
}

// ---------------- counting-sort scatter: CSR src lists by dst ---------------
__global__ void scatter_kernel(const int* __restrict__ src, const int* __restrict__ dst,
                               const int* __restrict__ indptr, int* __restrict__ cursor,
                               int* __restrict__ sorted_src) {
    int e = blockIdx.x * 256 + threadIdx.x;
    if (e < N_EDGES) {
        int d = dst[e];
        int p = indptr[d] + atomicAdd(&cursor[d], 1);
        sorted_src[p] = src[e];
    }
}

// ---------------- h[n, 0..255] = x[n,:] @ [W_emb | W_asn] -------------------
// block: 256 threads (one output col each), 16 nodes per block
__global__ void gemm_xw_kernel(const float* __restrict__ x, const float* __restrict__ W_emb,
                               const float* __restrict__ W_asn, float* __restrict__ h) {
    __shared__ float xs[16][128];
    int tid = threadIdx.x;
    int n0 = blockIdx.x * 16;
    for (int l = tid; l < 16 * 128; l += 256) {
        int r = l >> 7, c = l & 127;
        xs[r][c] = x[(n0 + r) * 128 + c];
    }
    __syncthreads();
    const float* __restrict__ W = (tid < 128) ? W_emb : W_asn;
    int c = tid & 127;
    float acc[16];
#pragma unroll
    for (int nn = 0; nn < 16; ++nn) acc[nn] = 0.f;
    for (int k = 0; k < 128; ++k) {
        float w = W[k * 128 + c];
#pragma unroll
        for (int nn = 0; nn < 16; ++nn) acc[nn] += xs[nn][k] * w;
    }
#pragma unroll
    for (int nn = 0; nn < 16; ++nn) h[(size_t)(n0 + nn) * 256 + tid] = acc[nn];
}

// ---------------- GCN aggregation + bias + relu / softmax -------------------
// one block (128 threads) per dst node; thread c handles channel c of both convs
__global__ void conv_kernel(const float* __restrict__ h, const int* __restrict__ indptr,
                            const int* __restrict__ sorted_src, const float* __restrict__ dinv,
                            const float* __restrict__ b_emb, const float* __restrict__ b_asn,
                            float* __restrict__ x_emb, float* __restrict__ S_out) {
    int d = blockIdx.x, c = threadIdx.x;
    int beg = indptr[d], end = indptr[d + 1];
    float di = dinv[d];
    float acc_e = 0.f, acc_a = 0.f;
    for (int e = beg; e < end; ++e) {
        int s = sorted_src[e];
        float w = dinv[s] * di;
        acc_e += h[(size_t)s * 256 + c] * w;
        acc_a += h[(size_t)s * 256 + 128 + c] * w;
    }
    // self loop
    float wll = di * di;
    acc_e += h[(size_t)d * 256 + c] * wll;
    acc_a += h[(size_t)d * 256 + 128 + c] * wll;
    acc_e += b_emb[c];
    acc_a += b_asn[c];
    x_emb[(size_t)d * 128 + c] = fmaxf(acc_e, 0.f);
    // softmax over the 128 asn channels (across the block's 128 threads)
    __shared__ float red[128];
    red[c] = acc_a;
    __syncthreads();
    for (int s2 = 64; s2 > 0; s2 >>= 1) {
        if (c < s2) red[c] = fmaxf(red[c], red[c + s2]);
        __syncthreads();
    }
    float m = red[0];
    __syncthreads();
    float ex = __expf(acc_a - m);
    red[c] = ex;
    __syncthreads();
    for (int s2 = 64; s2 > 0; s2 >>= 1) {
        if (c < s2) red[c] += red[c + s2];
        __syncthreads();
    }
    S_out[(size_t)d * 128 + c] = ex / red[0];
}

// ---------------- M_t[d, i] = sum over UNIQUE srcs s of d of S[s, i] --------
__global__ void mt_kernel(const float* __restrict__ S, const int* __restrict__ indptr,
                          const int* __restrict__ sorted_src, float* __restrict__ M_t) {
    __shared__ int ss[1024];
    __shared__ int uq[1024];
    int d = blockIdx.x, c = threadIdx.x;
    int beg = indptr[d];
    int len = indptr[d + 1] - beg;
    if (len > 1024) len = 1024;  // unreachable for Poisson(32); safety only
    for (int i = c; i < len; i += 128) ss[i] = sorted_src[beg + i];
    __syncthreads();
    for (int i = c; i < len; i += 128) {
        int s = ss[i];
        int u = 1;
        for (int j = 0; j < i; ++j)
            if (ss[j] == s) { u = 0; break; }
        uq[i] = u;
    }
    __syncthreads();
    float acc = 0.f;
    for (int e = 0; e < len; ++e)
        if (uq[e]) acc += S[(size_t)ss[e] * 128 + c];
    M_t[(size_t)d * 128 + c] = acc;
}

// ---------------- out[i,j] += sum_n A[n,i] * B[n,j]  (split-K, atomics) -----
// grid 64 blocks x 256 rows each; block tile 128x128, thread 8x8 micro-tile
__global__ void pool_gemm_kernel(const float* __restrict__ A, const float* __restrict__ B,
                                 float* __restrict__ out) {
    __shared__ float a_s[8][128];
    __shared__ float b_s[8][128];
    int tid = threadIdx.x;
    int ti = tid >> 4, tj = tid & 15;
    float acc[8][8];
#pragma unroll
    for (int i = 0; i < 8; ++i)
#pragma unroll
        for (int j = 0; j < 8; ++j) acc[i][j] = 0.f;
    int n0 = blockIdx.x * 256;
    for (int nb = 0; nb < 256; nb += 8) {
        for (int l = tid; l < 8 * 128; l += 256) {
            int r = l >> 7, cc = l & 127;
            a_s[r][cc] = A[(size_t)(n0 + nb + r) * 128 + cc];
            b_s[r][cc] = B[(size_t)(n0 + nb + r) * 128 + cc];
        }
        __syncthreads();
#pragma unroll
        for (int r = 0; r < 8; ++r) {
            float av[8], bv[8];
#pragma unroll
            for (int i = 0; i < 8; ++i) av[i] = a_s[r][ti * 8 + i];
#pragma unroll
            for (int j = 0; j < 8; ++j) bv[j] = b_s[r][tj * 8 + j];
#pragma unroll
            for (int i = 0; i < 8; ++i)
#pragma unroll
                for (int j = 0; j < 8; ++j) acc[i][j] += av[i] * bv[j];
        }
        __syncthreads();
    }
#pragma unroll
    for (int i = 0; i < 8; ++i)
#pragma unroll
        for (int j = 0; j < 8; ++j)
            atomicAdd(&out[(size_t)(ti * 8 + i) * 128 + (tj * 8 + j)], acc[i][j]);
}

extern "C" void kernel_launch(void* const* d_in, const int* in_sizes, int n_in,
                              void* d_out, int out_size, void* d_ws, size_t ws_size,
                              hipStream_t stream) {
    const float* x      = (const float*)d_in[0];
    const int*   ei     = (const int*)d_in[1];   // [2, E] int32 (JAX x64 disabled)
    const float* W_emb  = (const float*)d_in[2];
    const float* b_emb  = (const float*)d_in[3];
    const float* W_asn  = (const float*)d_in[4];
    const float* b_asn  = (const float*)d_in[5];
    const int* src = ei;
    const int* dst = ei + N_EDGES;

    float* out = (float*)d_out;
    float* S_out = out + 32768;           // S is outputs[2], after x_pooled(16384)+A_pooled(16384)

    // workspace layout (bytes)
    char* ws = (char*)d_ws;
    float* h       = (float*)(ws + 0);            // N*256*4 = 16,777,216
    float* x_emb   = (float*)(ws + 16777216);     // N*128*4 =  8,388,608
    int*   sorted  = (int*)  (ws + 25165824);     // E*4     =  2,097,152
    int*   count   = (int*)  (ws + 27262976);     // 65,536
    int*   indptr  = (int*)  (ws + 27328512);     // 65,792 (N+1 ints, padded)
    int*   cursor  = (int*)  (ws + 27394304);     // 65,536
    float* dinv    = (float*)(ws + 27459840);     // 65,536
    float* M_t     = h;                           // reuse h after conv_kernel is done

    hipMemsetAsync(count, 0, 65536, stream);
    hipMemsetAsync(cursor, 0, 65536, stream);
    hipMemsetAsync(d_out, 0, 32768 * sizeof(float), stream);  // x_pooled + A_pooled

    hist_kernel<<<2048, 256, 0, stream>>>(dst, count);
    scan_kernel<<<1, 256, 0, stream>>>(count, indptr);
    dinv_kernel<<<64, 256, 0, stream>>>(count, dinv);
    scatter_kernel<<<2048, 256, 0, stream>>>(src, dst, indptr, cursor, sorted);
    gemm_xw_kernel<<<1024, 256, 0, stream>>>(x, W_emb, W_asn, h);
    conv_kernel<<<16384, 128, 0, stream>>>(h, indptr, sorted, dinv, b_emb, b_asn, x_emb, S_out);
    mt_kernel<<<16384, 128, 0, stream>>>(S_out, indptr, sorted, M_t);
    pool_gemm_kernel<<<64, 256, 0, stream>>>(S_out, x_emb, out);          // x_pooled
    pool_gemm_kernel<<<64, 256, 0, stream>>>(M_t, S_out, out + 16384);    // A_pooled
}

// Round 2
// 312.718 us; speedup vs baseline: 1.4365x; 1.4365x over previous
//
#include <hip/hip_runtime.h>

#define N_NODES 16384
#define N_EDGES 524288

// ---------------- histogram of dst (deg counts, duplicates included) --------
__global__ void hist_kernel(const int* __restrict__ dst, int* __restrict__ count) {
    int e = blockIdx.x * 256 + threadIdx.x;
    if (e < N_EDGES) atomicAdd(&count[dst[e]], 1);
}

// -------- exclusive scan of 16384 counts -> indptr, plus dinv ---------------
__global__ void scan_kernel(const int* __restrict__ count, int* __restrict__ indptr,
                            float* __restrict__ dinv) {
    __shared__ int part[256];
    int t = threadIdx.x;
    int base = t * 64;
    int local[64];
    int s = 0;
#pragma unroll
    for (int i = 0; i < 64; ++i) { local[i] = s; s += count[base + i]; }
    part[t] = s;
    __syncthreads();
    for (int off = 1; off < 256; off <<= 1) {
        int v = (t >= off) ? part[t - off] : 0;
        __syncthreads();
        part[t] += v;
        __syncthreads();
    }
    int prefix = (t == 0) ? 0 : part[t - 1];
#pragma unroll
    for (int i = 0; i < 64; ++i) {
        indptr[base + i] = prefix + local[i];
        dinv[base + i] = rsqrtf((float)(count[base + i] + 1));
    }
    if (t == 255) indptr[N_NODES] = part[255];
}

// ---------------- counting-sort scatter: CSR src lists by dst ---------------
__global__ void scatter_kernel(const int* __restrict__ src, const int* __restrict__ dst,
                               const int* __restrict__ indptr, int* __restrict__ cursor,
                               int* __restrict__ sorted_src) {
    int e = blockIdx.x * 256 + threadIdx.x;
    if (e < N_EDGES) {
        int d = dst[e];
        int p = indptr[d] + atomicAdd(&cursor[d], 1);
        sorted_src[p] = src[e];
    }
}

// ---------------- h[N,256] = x[N,128] @ [W_emb | W_asn] ---------------------
// grid (128, 2): 128 m-tiles x {emb, asn}. 256 threads, 8x8 strided microtile.
__global__ void gemm_xw_kernel(const float* __restrict__ x, const float* __restrict__ W_emb,
                               const float* __restrict__ W_asn, float* __restrict__ h) {
    __shared__ float xs[128][129];   // xs[k][m], +1 pad: conflict-free transp. write
    __shared__ float ws_s[8][128];
    int tid = threadIdx.x;
    int ti = tid >> 4, tj = tid & 15;
    int m0 = blockIdx.x * 128;
    const float* __restrict__ W = blockIdx.y ? W_asn : W_emb;

    for (int l = tid; l < 128 * 128; l += 256) {
        int m = l >> 7, k = l & 127;
        xs[k][m] = x[(size_t)(m0 + m) * 128 + k];
    }

    float acc[8][8];
#pragma unroll
    for (int i = 0; i < 8; ++i)
#pragma unroll
        for (int j = 0; j < 8; ++j) acc[i][j] = 0.f;

    for (int kb = 0; kb < 128; kb += 8) {
        for (int l = tid; l < 8 * 128; l += 256) {
            int r = l >> 7, c = l & 127;
            ws_s[r][c] = W[(size_t)(kb + r) * 128 + c];
        }
        __syncthreads();
#pragma unroll
        for (int r = 0; r < 8; ++r) {
            float av[8], bv[8];
#pragma unroll
            for (int i = 0; i < 8; ++i) av[i] = xs[kb + r][ti + 16 * i];
#pragma unroll
            for (int j = 0; j < 8; ++j) bv[j] = ws_s[r][tj + 16 * j];
#pragma unroll
            for (int i = 0; i < 8; ++i)
#pragma unroll
                for (int j = 0; j < 8; ++j) acc[i][j] += av[i] * bv[j];
        }
        __syncthreads();
    }
#pragma unroll
    for (int i = 0; i < 8; ++i)
#pragma unroll
        for (int j = 0; j < 8; ++j)
            h[(size_t)(m0 + ti + 16 * i) * 256 + blockIdx.y * 128 + tj + 16 * j] = acc[i][j];
}

// ---------------- GCN aggregation + bias + relu / softmax -------------------
__global__ void conv_kernel(const float* __restrict__ h, const int* __restrict__ indptr,
                            const int* __restrict__ sorted_src, const float* __restrict__ dinv,
                            const float* __restrict__ b_emb, const float* __restrict__ b_asn,
                            float* __restrict__ x_emb, float* __restrict__ S_out) {
    int d = blockIdx.x, c = threadIdx.x;
    int beg = indptr[d], end = indptr[d + 1];
    float di = dinv[d];
    float acc_e = 0.f, acc_a = 0.f;
    for (int e = beg; e < end; ++e) {
        int s = sorted_src[e];
        float w = dinv[s] * di;
        acc_e += h[(size_t)s * 256 + c] * w;
        acc_a += h[(size_t)s * 256 + 128 + c] * w;
    }
    float wll = di * di;
    acc_e += h[(size_t)d * 256 + c] * wll;
    acc_a += h[(size_t)d * 256 + 128 + c] * wll;
    acc_e += b_emb[c];
    acc_a += b_asn[c];
    x_emb[(size_t)d * 128 + c] = fmaxf(acc_e, 0.f);

    __shared__ float red[128];
    red[c] = acc_a;
    __syncthreads();
    for (int s2 = 64; s2 > 0; s2 >>= 1) {
        if (c < s2) red[c] = fmaxf(red[c], red[c + s2]);
        __syncthreads();
    }
    float m = red[0];
    __syncthreads();
    float ex = __expf(acc_a - m);
    red[c] = ex;
    __syncthreads();
    for (int s2 = 64; s2 > 0; s2 >>= 1) {
        if (c < s2) red[c] += red[c + s2];
        __syncthreads();
    }
    S_out[(size_t)d * 128 + c] = ex / red[0];
}

// ---------------- M_t[d, i] = sum over UNIQUE srcs s of d of S[s, i] --------
__global__ void mt_kernel(const float* __restrict__ S, const int* __restrict__ indptr,
                          const int* __restrict__ sorted_src, float* __restrict__ M_t) {
    __shared__ int ss[1024];
    __shared__ int uq[1024];
    int d = blockIdx.x, c = threadIdx.x;
    int beg = indptr[d];
    int len = indptr[d + 1] - beg;
    if (len > 1024) len = 1024;
    for (int i = c; i < len; i += 128) ss[i] = sorted_src[beg + i];
    __syncthreads();
    for (int i = c; i < len; i += 128) {
        int s = ss[i];
        int u = 1;
        for (int j = 0; j < i; ++j)
            if (ss[j] == s) { u = 0; break; }
        uq[i] = u;
    }
    __syncthreads();
    float acc = 0.f;
    for (int e = 0; e < len; ++e)
        if (uq[e]) acc += S[(size_t)ss[e] * 128 + c];
    M_t[(size_t)d * 128 + c] = acc;
}

// ---- stage 1: partial[p] = A_chunk^T @ B_chunk  (chunk = 128 K-rows) -------
// grid (128, 2): y=0: A=S, B=x_emb (x_pooled); y=1: A=M_t, B=S (A_pooled)
__global__ void pool_stage1_kernel(const float* __restrict__ S, const float* __restrict__ x_emb,
                                   const float* __restrict__ M_t, float* __restrict__ part) {
    const float* __restrict__ A = blockIdx.y ? M_t : S;
    const float* __restrict__ B = blockIdx.y ? S : x_emb;
    float* __restrict__ out = part + (size_t)blockIdx.y * (128 * 16384) +
                              (size_t)blockIdx.x * 16384;
    __shared__ float a_s[8][128];
    __shared__ float b_s[8][128];
    int tid = threadIdx.x;
    int ti = tid >> 4, tj = tid & 15;
    float acc[8][8];
#pragma unroll
    for (int i = 0; i < 8; ++i)
#pragma unroll
        for (int j = 0; j < 8; ++j) acc[i][j] = 0.f;

    int n0 = blockIdx.x * 128;
    for (int nb = 0; nb < 128; nb += 8) {
        for (int l = tid; l < 8 * 128; l += 256) {
            int r = l >> 7, cc = l & 127;
            a_s[r][cc] = A[(size_t)(n0 + nb + r) * 128 + cc];
            b_s[r][cc] = B[(size_t)(n0 + nb + r) * 128 + cc];
        }
        __syncthreads();
#pragma unroll
        for (int r = 0; r < 8; ++r) {
            float av[8], bv[8];
#pragma unroll
            for (int i = 0; i < 8; ++i) av[i] = a_s[r][ti + 16 * i];
#pragma unroll
            for (int j = 0; j < 8; ++j) bv[j] = b_s[r][tj + 16 * j];
#pragma unroll
            for (int i = 0; i < 8; ++i)
#pragma unroll
                for (int j = 0; j < 8; ++j) acc[i][j] += av[i] * bv[j];
        }
        __syncthreads();
    }
#pragma unroll
    for (int i = 0; i < 8; ++i)
#pragma unroll
        for (int j = 0; j < 8; ++j)
            out[(size_t)(ti + 16 * i) * 128 + tj + 16 * j] = acc[i][j];
}

// ---- stage 2: out[idx] = sum_p partial[p][idx] -----------------------------
__global__ void pool_reduce_kernel(const float* __restrict__ part, float* __restrict__ out) {
    int idx = blockIdx.x * 256 + threadIdx.x;      // 0..32767
    int g = idx >> 14;                             // 0: x_pooled, 1: A_pooled
    int o = idx & 16383;
    const float* __restrict__ p = part + (size_t)g * (128 * 16384) + o;
    float s = 0.f;
#pragma unroll 8
    for (int c = 0; c < 128; ++c) s += p[(size_t)c * 16384];
    out[idx] = s;
}

extern "C" void kernel_launch(void* const* d_in, const int* in_sizes, int n_in,
                              void* d_out, int out_size, void* d_ws, size_t ws_size,
                              hipStream_t stream) {
    const float* x      = (const float*)d_in[0];
    const int*   ei     = (const int*)d_in[1];
    const float* W_emb  = (const float*)d_in[2];
    const float* b_emb  = (const float*)d_in[3];
    const float* W_asn  = (const float*)d_in[4];
    const float* b_asn  = (const float*)d_in[5];
    const int* src = ei;
    const int* dst = ei + N_EDGES;

    float* out = (float*)d_out;
    float* S_out = out + 32768;   // outputs: x_pooled(16384), A_pooled(16384), S(N*128)

    // workspace layout (bytes):
    char* ws = (char*)d_ws;
    float* h       = (float*)(ws + 0);            // N*256*4 = 16 MB; reused as partials
    float* part    = h;                           // 2 * 128 * 64KB = 16 MB (after conv)
    float* x_emb   = (float*)(ws + 16777216);     // 8 MB
    float* M_t     = (float*)(ws + 25165824);     // 8 MB
    int*   sorted  = (int*)  (ws + 33554432);     // 2 MB
    int*   count   = (int*)  (ws + 35651584);     // 64 KB
    int*   indptr  = (int*)  (ws + 35782656);     // 64 KB + 4
    int*   cursor  = (int*)  (ws + 35913728);     // 64 KB
    float* dinv    = (float*)(ws + 36044800);     // 64 KB

    hipMemsetAsync(count, 0, 65536, stream);
    hipMemsetAsync(cursor, 0, 65536, stream);

    hist_kernel<<<2048, 256, 0, stream>>>(dst, count);
    scan_kernel<<<1, 256, 0, stream>>>(count, indptr, dinv);
    scatter_kernel<<<2048, 256, 0, stream>>>(src, dst, indptr, cursor, sorted);
    gemm_xw_kernel<<<dim3(128, 2), 256, 0, stream>>>(x, W_emb, W_asn, h);
    conv_kernel<<<16384, 128, 0, stream>>>(h, indptr, sorted, dinv, b_emb, b_asn, x_emb, S_out);
    mt_kernel<<<16384, 128, 0, stream>>>(S_out, indptr, sorted, M_t);
    pool_stage1_kernel<<<dim3(128, 2), 256, 0, stream>>>(S_out, x_emb, M_t, part);
    pool_reduce_kernel<<<128, 256, 0, stream>>>(part, out);
}

// Round 3
// 259.724 us; speedup vs baseline: 1.7296x; 1.2040x over previous
//
#include <hip/hip_runtime.h>

#define N_NODES 16384
#define N_EDGES 524288

// ---------------- histogram of dst (deg counts, duplicates included) --------
__global__ void hist_kernel(const int* __restrict__ dst, int* __restrict__ count) {
    int e = blockIdx.x * 256 + threadIdx.x;
    if (e < N_EDGES) atomicAdd(&count[dst[e]], 1);
}

// -------- exclusive scan of 16384 counts -> indptr, plus dinv ---------------
__global__ void scan_kernel(const int* __restrict__ count, int* __restrict__ indptr,
                            float* __restrict__ dinv) {
    __shared__ int part[256];
    int t = threadIdx.x;
    int base = t * 64;
    int local[64];
    int s = 0;
#pragma unroll
    for (int i = 0; i < 64; ++i) { local[i] = s; s += count[base + i]; }
    part[t] = s;
    __syncthreads();
    for (int off = 1; off < 256; off <<= 1) {
        int v = (t >= off) ? part[t - off] : 0;
        __syncthreads();
        part[t] += v;
        __syncthreads();
    }
    int prefix = (t == 0) ? 0 : part[t - 1];
#pragma unroll
    for (int i = 0; i < 64; ++i) {
        indptr[base + i] = prefix + local[i];
        dinv[base + i] = rsqrtf((float)(count[base + i] + 1));
    }
    if (t == 255) indptr[N_NODES] = part[255];
}

// ---------------- counting-sort scatter: CSR src lists by dst ---------------
__global__ void scatter_kernel(const int* __restrict__ src, const int* __restrict__ dst,
                               const int* __restrict__ indptr, int* __restrict__ cursor,
                               int* __restrict__ sorted_src) {
    int e = blockIdx.x * 256 + threadIdx.x;
    if (e < N_EDGES) {
        int d = dst[e];
        int p = indptr[d] + atomicAdd(&cursor[d], 1);
        sorted_src[p] = src[e];
    }
}

// -------- h'[N,256] = (x[N,128] @ [W_emb | W_asn]) * dinv[row] --------------
// grid (128, 2): 128 m-tiles x {emb, asn}. 256 threads, 8x8 strided microtile.
__global__ void gemm_xw_kernel(const float* __restrict__ x, const float* __restrict__ W_emb,
                               const float* __restrict__ W_asn, const float* __restrict__ dinv,
                               float* __restrict__ h) {
    __shared__ float xs[128][129];   // xs[k][m]
    __shared__ float ws_s[8][128];
    int tid = threadIdx.x;
    int ti = tid >> 4, tj = tid & 15;
    int m0 = blockIdx.x * 128;
    const float* __restrict__ W = blockIdx.y ? W_asn : W_emb;

    for (int l = tid; l < 128 * 128; l += 256) {
        int m = l >> 7, k = l & 127;
        xs[k][m] = x[(size_t)(m0 + m) * 128 + k];
    }

    float acc[8][8];
#pragma unroll
    for (int i = 0; i < 8; ++i)
#pragma unroll
        for (int j = 0; j < 8; ++j) acc[i][j] = 0.f;

    for (int kb = 0; kb < 128; kb += 8) {
        for (int l = tid; l < 8 * 128; l += 256) {
            int r = l >> 7, c = l & 127;
            ws_s[r][c] = W[(size_t)(kb + r) * 128 + c];
        }
        __syncthreads();
#pragma unroll
        for (int r = 0; r < 8; ++r) {
            float av[8], bv[8];
#pragma unroll
            for (int i = 0; i < 8; ++i) av[i] = xs[kb + r][ti + 16 * i];
#pragma unroll
            for (int j = 0; j < 8; ++j) bv[j] = ws_s[r][tj + 16 * j];
#pragma unroll
            for (int i = 0; i < 8; ++i)
#pragma unroll
                for (int j = 0; j < 8; ++j) acc[i][j] += av[i] * bv[j];
        }
        __syncthreads();
    }
    float dm[8];
#pragma unroll
    for (int i = 0; i < 8; ++i) dm[i] = dinv[m0 + ti + 16 * i];
#pragma unroll
    for (int i = 0; i < 8; ++i)
#pragma unroll
        for (int j = 0; j < 8; ++j)
            h[(size_t)(m0 + ti + 16 * i) * 256 + blockIdx.y * 128 + tj + 16 * j] =
                acc[i][j] * dm[i];
}

// ---------------- GCN aggregation + bias + relu / softmax -------------------
// one WAVE per (node, role): role 0 = emb (relu), role 1 = asn (softmax).
// h is pre-scaled by dinv[src]; final scale by dinv[d]. No __syncthreads.
__global__ void conv_kernel(const float* __restrict__ h, const int* __restrict__ indptr,
                            const int* __restrict__ sorted_src, const float* __restrict__ dinv,
                            const float* __restrict__ b_emb, const float* __restrict__ b_asn,
                            float* __restrict__ x_emb, float* __restrict__ S_out) {
    const float2* __restrict__ hp = (const float2*)h;
    int wv = threadIdx.x >> 6, lane = threadIdx.x & 63;
    int task = blockIdx.x * 4 + wv;           // 0..32767
    int d = task >> 1, role = task & 1;
    int beg = indptr[d], end = indptr[d + 1];
    float di = dinv[d];
    int off = role * 64 + lane;
    float ax = 0.f, ay = 0.f;
    for (int ch = beg; ch < end; ch += 64) {
        int take = end - ch; if (take > 64) take = 64;
        int myi = sorted_src[ch + (lane < take ? lane : 0)];
        int i = 0;
        for (; i + 4 <= take; i += 4) {
            int s0 = __shfl(myi, i),     s1 = __shfl(myi, i + 1);
            int s2 = __shfl(myi, i + 2), s3 = __shfl(myi, i + 3);
            float2 v0 = hp[(size_t)s0 * 128 + off];
            float2 v1 = hp[(size_t)s1 * 128 + off];
            float2 v2 = hp[(size_t)s2 * 128 + off];
            float2 v3 = hp[(size_t)s3 * 128 + off];
            ax += (v0.x + v1.x) + (v2.x + v3.x);
            ay += (v0.y + v1.y) + (v2.y + v3.y);
        }
        for (; i < take; ++i) {
            int s = __shfl(myi, i);
            float2 v = hp[(size_t)s * 128 + off];
            ax += v.x; ay += v.y;
        }
    }
    float2 vd = hp[(size_t)d * 128 + off];    // self loop (h'[d]*di = h[d]*di^2)
    ax += vd.x; ay += vd.y;
    ax *= di; ay *= di;
    const float2* __restrict__ bp = (const float2*)(role ? b_asn : b_emb);
    float2 bb = bp[lane];
    ax += bb.x; ay += bb.y;
    if (role == 0) {
        float2 o; o.x = fmaxf(ax, 0.f); o.y = fmaxf(ay, 0.f);
        ((float2*)x_emb)[(size_t)d * 64 + lane] = o;
    } else {
        float m = fmaxf(ax, ay);
#pragma unroll
        for (int o2 = 32; o2; o2 >>= 1) m = fmaxf(m, __shfl_xor(m, o2));
        float e0 = __expf(ax - m), e1 = __expf(ay - m);
        float s = e0 + e1;
#pragma unroll
        for (int o2 = 32; o2; o2 >>= 1) s += __shfl_xor(s, o2);
        float inv = 1.f / s;
        float2 o; o.x = e0 * inv; o.y = e1 * inv;
        ((float2*)S_out)[(size_t)d * 64 + lane] = o;
    }
}

// ---------------- M_t[d, i] = sum over UNIQUE srcs s of d of S[s, i] --------
// one wave per node; dedup marks duplicates as -1 in the LDS list (first
// occurrence never marked -> deterministic); branchless predicated gather.
__global__ void mt_kernel(const float* __restrict__ S, const int* __restrict__ indptr,
                          const int* __restrict__ sorted_src, float* __restrict__ M_t) {
    __shared__ int ss[4][1024];
    const float2* __restrict__ Sp = (const float2*)S;
    int wv = threadIdx.x >> 6, lane = threadIdx.x & 63;
    int d = blockIdx.x * 4 + wv;
    int beg = indptr[d];
    int len = indptr[d + 1] - beg;
    if (len > 1024) len = 1024;
    for (int i = lane; i < len; i += 64) ss[wv][i] = sorted_src[beg + i];
    __syncthreads();
    for (int i = lane; i < len; i += 64) {
        int s = ss[wv][i];
        for (int j = 0; j < i; ++j)
            if (ss[wv][j] == s) { ss[wv][i] = -1; break; }
    }
    __syncthreads();
    float ax = 0.f, ay = 0.f;
    for (int ch = 0; ch < len; ch += 64) {
        int take = len - ch; if (take > 64) take = 64;
        int myv = ss[wv][ch + (lane < take ? lane : 0)];
        int i = 0;
        for (; i + 4 <= take; i += 4) {
            int s0 = __shfl(myv, i),     s1 = __shfl(myv, i + 1);
            int s2 = __shfl(myv, i + 2), s3 = __shfl(myv, i + 3);
            float m0 = s0 >= 0 ? 1.f : 0.f, m1 = s1 >= 0 ? 1.f : 0.f;
            float m2 = s2 >= 0 ? 1.f : 0.f, m3 = s3 >= 0 ? 1.f : 0.f;
            float2 v0 = Sp[(size_t)(s0 >= 0 ? s0 : 0) * 64 + lane];
            float2 v1 = Sp[(size_t)(s1 >= 0 ? s1 : 0) * 64 + lane];
            float2 v2 = Sp[(size_t)(s2 >= 0 ? s2 : 0) * 64 + lane];
            float2 v3 = Sp[(size_t)(s3 >= 0 ? s3 : 0) * 64 + lane];
            ax += (v0.x * m0 + v1.x * m1) + (v2.x * m2 + v3.x * m3);
            ay += (v0.y * m0 + v1.y * m1) + (v2.y * m2 + v3.y * m3);
        }
        for (; i < take; ++i) {
            int s = __shfl(myv, i);
            if (s >= 0) {
                float2 v = Sp[(size_t)s * 64 + lane];
                ax += v.x; ay += v.y;
            }
        }
    }
    ((float2*)M_t)[(size_t)d * 64 + lane] = make_float2(ax, ay);
}

// ---- stage 1: partial[p] = A_chunk^T @ B_chunk  (chunk = 128 K-rows) -------
__global__ void pool_stage1_kernel(const float* __restrict__ S, const float* __restrict__ x_emb,
                                   const float* __restrict__ M_t, float* __restrict__ part) {
    const float* __restrict__ A = blockIdx.y ? M_t : S;
    const float* __restrict__ B = blockIdx.y ? S : x_emb;
    float* __restrict__ out = part + (size_t)blockIdx.y * (128 * 16384) +
                              (size_t)blockIdx.x * 16384;
    __shared__ float a_s[8][128];
    __shared__ float b_s[8][128];
    int tid = threadIdx.x;
    int ti = tid >> 4, tj = tid & 15;
    float acc[8][8];
#pragma unroll
    for (int i = 0; i < 8; ++i)
#pragma unroll
        for (int j = 0; j < 8; ++j) acc[i][j] = 0.f;

    int n0 = blockIdx.x * 128;
    for (int nb = 0; nb < 128; nb += 8) {
        for (int l = tid; l < 8 * 128; l += 256) {
            int r = l >> 7, cc = l & 127;
            a_s[r][cc] = A[(size_t)(n0 + nb + r) * 128 + cc];
            b_s[r][cc] = B[(size_t)(n0 + nb + r) * 128 + cc];
        }
        __syncthreads();
#pragma unroll
        for (int r = 0; r < 8; ++r) {
            float av[8], bv[8];
#pragma unroll
            for (int i = 0; i < 8; ++i) av[i] = a_s[r][ti + 16 * i];
#pragma unroll
            for (int j = 0; j < 8; ++j) bv[j] = b_s[r][tj + 16 * j];
#pragma unroll
            for (int i = 0; i < 8; ++i)
#pragma unroll
                for (int j = 0; j < 8; ++j) acc[i][j] += av[i] * bv[j];
        }
        __syncthreads();
    }
#pragma unroll
    for (int i = 0; i < 8; ++i)
#pragma unroll
        for (int j = 0; j < 8; ++j)
            out[(size_t)(ti + 16 * i) * 128 + tj + 16 * j] = acc[i][j];
}

// ---- stage 2: out[idx] = sum_p partial[p][idx] -----------------------------
__global__ void pool_reduce_kernel(const float* __restrict__ part, float* __restrict__ out) {
    int idx = blockIdx.x * 256 + threadIdx.x;      // 0..32767
    int g = idx >> 14;
    int o = idx & 16383;
    const float* __restrict__ p = part + (size_t)g * (128 * 16384) + o;
    float s = 0.f;
#pragma unroll 8
    for (int c = 0; c < 128; ++c) s += p[(size_t)c * 16384];
    out[idx] = s;
}

extern "C" void kernel_launch(void* const* d_in, const int* in_sizes, int n_in,
                              void* d_out, int out_size, void* d_ws, size_t ws_size,
                              hipStream_t stream) {
    const float* x      = (const float*)d_in[0];
    const int*   ei     = (const int*)d_in[1];
    const float* W_emb  = (const float*)d_in[2];
    const float* b_emb  = (const float*)d_in[3];
    const float* W_asn  = (const float*)d_in[4];
    const float* b_asn  = (const float*)d_in[5];
    const int* src = ei;
    const int* dst = ei + N_EDGES;

    float* out = (float*)d_out;
    float* S_out = out + 32768;   // outputs: x_pooled(16384), A_pooled(16384), S(N*128)

    char* ws = (char*)d_ws;
    float* h       = (float*)(ws + 0);            // 16 MB; reused as partials
    float* part    = h;
    float* x_emb   = (float*)(ws + 16777216);     // 8 MB
    float* M_t     = (float*)(ws + 25165824);     // 8 MB
    int*   sorted  = (int*)  (ws + 33554432);     // 2 MB
    int*   count   = (int*)  (ws + 35651584);
    int*   indptr  = (int*)  (ws + 35782656);
    int*   cursor  = (int*)  (ws + 35913728);
    float* dinv    = (float*)(ws + 36044800);

    hipMemsetAsync(count, 0, 65536, stream);
    hipMemsetAsync(cursor, 0, 65536, stream);

    hist_kernel<<<2048, 256, 0, stream>>>(dst, count);
    scan_kernel<<<1, 256, 0, stream>>>(count, indptr, dinv);
    scatter_kernel<<<2048, 256, 0, stream>>>(src, dst, indptr, cursor, sorted);
    gemm_xw_kernel<<<dim3(128, 2), 256, 0, stream>>>(x, W_emb, W_asn, dinv, h);
    conv_kernel<<<8192, 256, 0, stream>>>(h, indptr, sorted, dinv, b_emb, b_asn, x_emb, S_out);
    mt_kernel<<<4096, 256, 0, stream>>>(S_out, indptr, sorted, M_t);
    pool_stage1_kernel<<<dim3(128, 2), 256, 0, stream>>>(S_out, x_emb, M_t, part);
    pool_reduce_kernel<<<128, 256, 0, stream>>>(part, out);
}

// Round 4
// 225.914 us; speedup vs baseline: 1.9885x; 1.1497x over previous
//
#include <hip/hip_runtime.h>

#define N_NODES 16384
#define N_EDGES 524288

__device__ __forceinline__ ushort f2bf(float a) {
    uint u = __float_as_uint(a);
    return (ushort)((u + 0x7fff + ((u >> 16) & 1)) >> 16);
}
__device__ __forceinline__ uint pack2bf(float a, float b) {
    return (uint)f2bf(a) | ((uint)f2bf(b) << 16);
}
__device__ __forceinline__ float bflo(uint v) { return __uint_as_float(v << 16); }
__device__ __forceinline__ float bfhi(uint v) { return __uint_as_float(v & 0xffff0000u); }

// ---------------- histogram of dst (deg counts, duplicates included) --------
__global__ void hist_kernel(const int* __restrict__ dst, int* __restrict__ count) {
    int e = blockIdx.x * 256 + threadIdx.x;
    if (e < N_EDGES) atomicAdd(&count[dst[e]], 1);
}

// -------- exclusive scan of 16384 counts -> indptr, plus dinv ---------------
__global__ void scan_kernel(const int* __restrict__ count, int* __restrict__ indptr,
                            float* __restrict__ dinv) {
    __shared__ int part[256];
    int t = threadIdx.x;
    int base = t * 64;
    int local[64];
    int s = 0;
#pragma unroll
    for (int i = 0; i < 64; ++i) { local[i] = s; s += count[base + i]; }
    part[t] = s;
    __syncthreads();
    for (int off = 1; off < 256; off <<= 1) {
        int v = (t >= off) ? part[t - off] : 0;
        __syncthreads();
        part[t] += v;
        __syncthreads();
    }
    int prefix = (t == 0) ? 0 : part[t - 1];
#pragma unroll
    for (int i = 0; i < 64; ++i) {
        indptr[base + i] = prefix + local[i];
        dinv[base + i] = rsqrtf((float)(count[base + i] + 1));
    }
    if (t == 255) indptr[N_NODES] = part[255];
}

// ---------------- counting-sort scatter: CSR src lists by dst ---------------
__global__ void scatter_kernel(const int* __restrict__ src, const int* __restrict__ dst,
                               const int* __restrict__ indptr, int* __restrict__ cursor,
                               int* __restrict__ sorted_src) {
    int e = blockIdx.x * 256 + threadIdx.x;
    if (e < N_EDGES) {
        int d = dst[e];
        int p = indptr[d] + atomicAdd(&cursor[d], 1);
        sorted_src[p] = src[e];
    }
}

// ---- h'[N,256](bf16) = (x[N,128] @ [W_emb | W_asn]) * dinv[row] ------------
__global__ void gemm_xw_kernel(const float* __restrict__ x, const float* __restrict__ W_emb,
                               const float* __restrict__ W_asn, const float* __restrict__ dinv,
                               ushort* __restrict__ h) {
    __shared__ float xs[128][129];
    __shared__ float ws_s[8][128];
    int tid = threadIdx.x;
    int ti = tid >> 4, tj = tid & 15;
    int m0 = blockIdx.x * 128;
    const float* __restrict__ W = blockIdx.y ? W_asn : W_emb;

    for (int l = tid; l < 128 * 128; l += 256) {
        int m = l >> 7, k = l & 127;
        xs[k][m] = x[(size_t)(m0 + m) * 128 + k];
    }

    float acc[8][8];
#pragma unroll
    for (int i = 0; i < 8; ++i)
#pragma unroll
        for (int j = 0; j < 8; ++j) acc[i][j] = 0.f;

    for (int kb = 0; kb < 128; kb += 8) {
        for (int l = tid; l < 8 * 128; l += 256) {
            int r = l >> 7, c = l & 127;
            ws_s[r][c] = W[(size_t)(kb + r) * 128 + c];
        }
        __syncthreads();
#pragma unroll
        for (int r = 0; r < 8; ++r) {
            float av[8], bv[8];
#pragma unroll
            for (int i = 0; i < 8; ++i) av[i] = xs[kb + r][ti + 16 * i];
#pragma unroll
            for (int j = 0; j < 8; ++j) bv[j] = ws_s[r][tj + 16 * j];
#pragma unroll
            for (int i = 0; i < 8; ++i)
#pragma unroll
                for (int j = 0; j < 8; ++j) acc[i][j] += av[i] * bv[j];
        }
        __syncthreads();
    }
    float dm[8];
#pragma unroll
    for (int i = 0; i < 8; ++i) dm[i] = dinv[m0 + ti + 16 * i];
#pragma unroll
    for (int i = 0; i < 8; ++i)
#pragma unroll
        for (int j = 0; j < 8; ++j)
            h[(size_t)(m0 + ti + 16 * i) * 256 + blockIdx.y * 128 + tj + 16 * j] =
                f2bf(acc[i][j] * dm[i]);
}

// ---------------- GCN aggregation + bias + relu / softmax -------------------
// one WAVE per (node, role). h is bf16, pre-scaled by dinv[src].
__global__ void conv_kernel(const ushort* __restrict__ h, const int* __restrict__ indptr,
                            const int* __restrict__ sorted_src, const float* __restrict__ dinv,
                            const float* __restrict__ b_emb, const float* __restrict__ b_asn,
                            float* __restrict__ x_emb, float* __restrict__ S_out,
                            uint* __restrict__ S_bf) {
    const uint* __restrict__ hp = (const uint*)h;   // 2 bf16 per uint, 128 uints/row
    int wv = threadIdx.x >> 6, lane = threadIdx.x & 63;
    int task = blockIdx.x * 4 + wv;
    int d = task >> 1, role = task & 1;
    int beg = indptr[d], end = indptr[d + 1];
    float di = dinv[d];
    int off = role * 64 + lane;
    float ax = 0.f, ay = 0.f;
    for (int ch = beg; ch < end; ch += 64) {
        int take = end - ch; if (take > 64) take = 64;
        int myi = sorted_src[ch + (lane < take ? lane : 0)];
        int i = 0;
        for (; i + 4 <= take; i += 4) {
            int s0 = __shfl(myi, i),     s1 = __shfl(myi, i + 1);
            int s2 = __shfl(myi, i + 2), s3 = __shfl(myi, i + 3);
            uint v0 = hp[(size_t)s0 * 128 + off];
            uint v1 = hp[(size_t)s1 * 128 + off];
            uint v2 = hp[(size_t)s2 * 128 + off];
            uint v3 = hp[(size_t)s3 * 128 + off];
            ax += (bflo(v0) + bflo(v1)) + (bflo(v2) + bflo(v3));
            ay += (bfhi(v0) + bfhi(v1)) + (bfhi(v2) + bfhi(v3));
        }
        for (; i < take; ++i) {
            int s = __shfl(myi, i);
            uint v = hp[(size_t)s * 128 + off];
            ax += bflo(v); ay += bfhi(v);
        }
    }
    uint vd = hp[(size_t)d * 128 + off];     // self loop
    ax += bflo(vd); ay += bfhi(vd);
    ax *= di; ay *= di;
    const float2* __restrict__ bp = (const float2*)(role ? b_asn : b_emb);
    float2 bb = bp[lane];
    ax += bb.x; ay += bb.y;
    if (role == 0) {
        float2 o; o.x = fmaxf(ax, 0.f); o.y = fmaxf(ay, 0.f);
        ((float2*)x_emb)[(size_t)d * 64 + lane] = o;
    } else {
        float m = fmaxf(ax, ay);
#pragma unroll
        for (int o2 = 32; o2; o2 >>= 1) m = fmaxf(m, __shfl_xor(m, o2));
        float e0 = __expf(ax - m), e1 = __expf(ay - m);
        float s = e0 + e1;
#pragma unroll
        for (int o2 = 32; o2; o2 >>= 1) s += __shfl_xor(s, o2);
        float inv = 1.f / s;
        float p0 = e0 * inv, p1 = e1 * inv;
        ((float2*)S_out)[(size_t)d * 64 + lane] = make_float2(p0, p1);
        S_bf[(size_t)d * 64 + lane] = pack2bf(p0, p1);
    }
}

// ---------------- M_t[d, i] = sum over UNIQUE srcs s of d of S[s, i] --------
__global__ void mt_kernel(const uint* __restrict__ S_bf, const int* __restrict__ indptr,
                          const int* __restrict__ sorted_src, float* __restrict__ M_t) {
    __shared__ int ss[4][1024];
    int wv = threadIdx.x >> 6, lane = threadIdx.x & 63;
    int d = blockIdx.x * 4 + wv;
    int beg = indptr[d];
    int len = indptr[d + 1] - beg;
    if (len > 1024) len = 1024;
    for (int i = lane; i < len; i += 64) ss[wv][i] = sorted_src[beg + i];
    __syncthreads();
    for (int i = lane; i < len; i += 64) {
        int s = ss[wv][i];
        for (int j = 0; j < i; ++j)
            if (ss[wv][j] == s) { ss[wv][i] = -1; break; }
    }
    __syncthreads();
    float ax = 0.f, ay = 0.f;
    for (int ch = 0; ch < len; ch += 64) {
        int take = len - ch; if (take > 64) take = 64;
        int myv = ss[wv][ch + (lane < take ? lane : 0)];
        int i = 0;
        for (; i + 4 <= take; i += 4) {
            int s0 = __shfl(myv, i),     s1 = __shfl(myv, i + 1);
            int s2 = __shfl(myv, i + 2), s3 = __shfl(myv, i + 3);
            float m0 = s0 >= 0 ? 1.f : 0.f, m1 = s1 >= 0 ? 1.f : 0.f;
            float m2 = s2 >= 0 ? 1.f : 0.f, m3 = s3 >= 0 ? 1.f : 0.f;
            uint v0 = S_bf[(size_t)(s0 >= 0 ? s0 : 0) * 64 + lane];
            uint v1 = S_bf[(size_t)(s1 >= 0 ? s1 : 0) * 64 + lane];
            uint v2 = S_bf[(size_t)(s2 >= 0 ? s2 : 0) * 64 + lane];
            uint v3 = S_bf[(size_t)(s3 >= 0 ? s3 : 0) * 64 + lane];
            ax += (bflo(v0) * m0 + bflo(v1) * m1) + (bflo(v2) * m2 + bflo(v3) * m3);
            ay += (bfhi(v0) * m0 + bfhi(v1) * m1) + (bfhi(v2) * m2 + bfhi(v3) * m3);
        }
        for (; i < take; ++i) {
            int s = __shfl(myv, i);
            if (s >= 0) {
                uint v = S_bf[(size_t)s * 64 + lane];
                ax += bflo(v); ay += bfhi(v);
            }
        }
    }
    ((float2*)M_t)[(size_t)d * 64 + lane] = make_float2(ax, ay);
}

// ---- stage 1: partial[p] = A_chunk^T @ B_chunk  (chunk = 128 K-rows) -------
__global__ void pool_stage1_kernel(const float* __restrict__ S, const float* __restrict__ x_emb,
                                   const float* __restrict__ M_t, float* __restrict__ part) {
    const float* __restrict__ A = blockIdx.y ? M_t : S;
    const float* __restrict__ B = blockIdx.y ? S : x_emb;
    float* __restrict__ out = part + (size_t)blockIdx.y * (128 * 16384) +
                              (size_t)blockIdx.x * 16384;
    __shared__ float a_s[8][128];
    __shared__ float b_s[8][128];
    int tid = threadIdx.x;
    int ti = tid >> 4, tj = tid & 15;
    float acc[8][8];
#pragma unroll
    for (int i = 0; i < 8; ++i)
#pragma unroll
        for (int j = 0; j < 8; ++j) acc[i][j] = 0.f;

    int n0 = blockIdx.x * 128;
    for (int nb = 0; nb < 128; nb += 8) {
        for (int l = tid; l < 8 * 128; l += 256) {
            int r = l >> 7, cc = l & 127;
            a_s[r][cc] = A[(size_t)(n0 + nb + r) * 128 + cc];
            b_s[r][cc] = B[(size_t)(n0 + nb + r) * 128 + cc];
        }
        __syncthreads();
#pragma unroll
        for (int r = 0; r < 8; ++r) {
            float av[8], bv[8];
#pragma unroll
            for (int i = 0; i < 8; ++i) av[i] = a_s[r][ti + 16 * i];
#pragma unroll
            for (int j = 0; j < 8; ++j) bv[j] = b_s[r][tj + 16 * j];
#pragma unroll
            for (int i = 0; i < 8; ++i)
#pragma unroll
                for (int j = 0; j < 8; ++j) acc[i][j] += av[i] * bv[j];
        }
        __syncthreads();
    }
#pragma unroll
    for (int i = 0; i < 8; ++i)
#pragma unroll
        for (int j = 0; j < 8; ++j)
            out[(size_t)(ti + 16 * i) * 128 + tj + 16 * j] = acc[i][j];
}

// ---- stage 2: out[idx] = sum_p partial[p][idx] -----------------------------
__global__ void pool_reduce_kernel(const float* __restrict__ part, float* __restrict__ out) {
    int idx = blockIdx.x * 256 + threadIdx.x;
    int g = idx >> 14;
    int o = idx & 16383;
    const float* __restrict__ p = part + (size_t)g * (128 * 16384) + o;
    float s = 0.f;
#pragma unroll 8
    for (int c = 0; c < 128; ++c) s += p[(size_t)c * 16384];
    out[idx] = s;
}

extern "C" void kernel_launch(void* const* d_in, const int* in_sizes, int n_in,
                              void* d_out, int out_size, void* d_ws, size_t ws_size,
                              hipStream_t stream) {
    const float* x      = (const float*)d_in[0];
    const int*   ei     = (const int*)d_in[1];
    const float* W_emb  = (const float*)d_in[2];
    const float* b_emb  = (const float*)d_in[3];
    const float* W_asn  = (const float*)d_in[4];
    const float* b_asn  = (const float*)d_in[5];
    const int* src = ei;
    const int* dst = ei + N_EDGES;

    float* out = (float*)d_out;
    float* S_out = out + 32768;   // outputs: x_pooled(16384), A_pooled(16384), S(N*128)

    // workspace layout (sequential-liveness overlapped):
    //   [0,8M)   h bf16        (gemm -> conv)
    //   [8M,12M) S_bf16        (conv -> mt)
    //   [0,16M)  part          (stage1 -> reduce; h and S_bf dead by then)
    //   [16M,24M) x_emb, [24M,32M) M_t, [32M,34M) sorted, [34M+) small arrays
    char* ws = (char*)d_ws;
    ushort* h      = (ushort*)(ws + 0);
    uint*   S_bf   = (uint*)  (ws + 8388608);
    float*  part   = (float*) (ws + 0);
    float*  x_emb  = (float*) (ws + 16777216);
    float*  M_t    = (float*) (ws + 25165824);
    int*    sorted = (int*)   (ws + 33554432);
    int*    count  = (int*)   (ws + 35651584);
    int*    indptr = (int*)   (ws + 35717120);
    int*    cursor = (int*)   (ws + 35848192);
    float*  dinv   = (float*) (ws + 35913728);

    hipMemsetAsync(count, 0, 65536, stream);
    hipMemsetAsync(cursor, 0, 65536, stream);

    hist_kernel<<<2048, 256, 0, stream>>>(dst, count);
    scan_kernel<<<1, 256, 0, stream>>>(count, indptr, dinv);
    scatter_kernel<<<2048, 256, 0, stream>>>(src, dst, indptr, cursor, sorted);
    gemm_xw_kernel<<<dim3(128, 2), 256, 0, stream>>>(x, W_emb, W_asn, dinv, h);
    conv_kernel<<<8192, 256, 0, stream>>>(h, indptr, sorted, dinv, b_emb, b_asn,
                                          x_emb, S_out, S_bf);
    mt_kernel<<<4096, 256, 0, stream>>>(S_bf, indptr, sorted, M_t);
    pool_stage1_kernel<<<dim3(128, 2), 256, 0, stream>>>(S_out, x_emb, M_t, part);
    pool_reduce_kernel<<<128, 256, 0, stream>>>(part, out);
}

// Round 5
// 191.685 us; speedup vs baseline: 2.3436x; 1.1786x over previous
//
#include <hip/hip_runtime.h>

#define N_NODES 16384
#define N_EDGES 524288

typedef short bf16x8 __attribute__((ext_vector_type(8)));
typedef float f32x4 __attribute__((ext_vector_type(4)));

__device__ __forceinline__ ushort f2bf(float a) {
    uint u = __float_as_uint(a);
    return (ushort)((u + 0x7fff + ((u >> 16) & 1)) >> 16);
}
__device__ __forceinline__ uint pack2bf(float a, float b) {
    return (uint)f2bf(a) | ((uint)f2bf(b) << 16);
}
__device__ __forceinline__ float bflo(uint v) { return __uint_as_float(v << 16); }
__device__ __forceinline__ float bfhi(uint v) { return __uint_as_float(v & 0xffff0000u); }

// ---------------- histogram of dst ------------------------------------------
__global__ void hist_kernel(const int* __restrict__ dst, int* __restrict__ count) {
    int e = blockIdx.x * 256 + threadIdx.x;
    if (e < N_EDGES) atomicAdd(&count[dst[e]], 1);
}

// -------- exclusive scan -> indptr, plus dinv -------------------------------
__global__ void scan_kernel(const int* __restrict__ count, int* __restrict__ indptr,
                            float* __restrict__ dinv) {
    __shared__ int part[256];
    int t = threadIdx.x;
    int base = t * 64;
    int local[64];
    int s = 0;
#pragma unroll
    for (int i = 0; i < 64; ++i) { local[i] = s; s += count[base + i]; }
    part[t] = s;
    __syncthreads();
    for (int off = 1; off < 256; off <<= 1) {
        int v = (t >= off) ? part[t - off] : 0;
        __syncthreads();
        part[t] += v;
        __syncthreads();
    }
    int prefix = (t == 0) ? 0 : part[t - 1];
#pragma unroll
    for (int i = 0; i < 64; ++i) {
        indptr[base + i] = prefix + local[i];
        dinv[base + i] = rsqrtf((float)(count[base + i] + 1));
    }
    if (t == 255) indptr[N_NODES] = part[255];
}

// ---------------- counting-sort scatter -------------------------------------
__global__ void scatter_kernel(const int* __restrict__ src, const int* __restrict__ dst,
                               const int* __restrict__ indptr, int* __restrict__ cursor,
                               int* __restrict__ sorted_src) {
    int e = blockIdx.x * 256 + threadIdx.x;
    if (e < N_EDGES) {
        int d = dst[e];
        int p = indptr[d] + atomicAdd(&cursor[d], 1);
        sorted_src[p] = src[e];
    }
}

// ---------------- x -> bf16 -------------------------------------------------
__global__ void cvt_x_kernel(const float* __restrict__ x, ushort* __restrict__ x_bf) {
    int i = (blockIdx.x * 256 + threadIdx.x) * 4;
    float4 v = *(const float4*)(x + i);
    ushort4 o;
    o.x = f2bf(v.x); o.y = f2bf(v.y); o.z = f2bf(v.z); o.w = f2bf(v.w);
    *(ushort4*)(x_bf + i) = o;
}

// ---------------- pack W^T bf16: wT[n][k], n<128 emb, else asn ---------------
__global__ void cvt_w_kernel(const float* __restrict__ W_emb, const float* __restrict__ W_asn,
                             ushort* __restrict__ wT) {
    int idx = blockIdx.x * 256 + threadIdx.x;   // 32768
    int k = idx >> 8, n = idx & 255;
    float v = n < 128 ? W_emb[k * 128 + n] : W_asn[k * 128 + (n - 128)];
    wT[(size_t)n * 128 + k] = f2bf(v);
}

// ------ h[N,256](bf16) = (x_bf @ wT^T) * dinv[row] via MFMA ------------------
// 256 blocks x 512 thr (8 waves: 2m x 4n). Wave tile 32x64. K=128.
__global__ __launch_bounds__(512) void gemm_xw_mfma(
        const ushort* __restrict__ x_bf, const ushort* __restrict__ wT,
        const float* __restrict__ dinv, ushort* __restrict__ h) {
    int l = threadIdx.x & 63, w = threadIdx.x >> 6;
    int m0 = blockIdx.x * 64 + (w >> 2) * 32;
    int n0 = (w & 3) * 64;
    int lr = l & 15, lk = (l >> 4) * 8;
    f32x4 acc[2][4] = {};
#pragma unroll
    for (int kk = 0; kk < 128; kk += 32) {
        bf16x8 a[2], b[4];
#pragma unroll
        for (int fm = 0; fm < 2; ++fm)
            a[fm] = *(const bf16x8*)(x_bf + (size_t)(m0 + fm * 16 + lr) * 128 + kk + lk);
#pragma unroll
        for (int fn = 0; fn < 4; ++fn)
            b[fn] = *(const bf16x8*)(wT + (size_t)(n0 + fn * 16 + lr) * 128 + kk + lk);
#pragma unroll
        for (int fm = 0; fm < 2; ++fm)
#pragma unroll
            for (int fn = 0; fn < 4; ++fn)
                acc[fm][fn] = __builtin_amdgcn_mfma_f32_16x16x32_bf16(
                    a[fm], b[fn], acc[fm][fn], 0, 0, 0);
    }
    int rbase = (l >> 4) * 4;
#pragma unroll
    for (int fm = 0; fm < 2; ++fm)
#pragma unroll
        for (int r = 0; r < 4; ++r) {
            int row = m0 + fm * 16 + rbase + r;
            float dv = dinv[row];
#pragma unroll
            for (int fn = 0; fn < 4; ++fn)
                h[(size_t)row * 256 + n0 + fn * 16 + lr] = f2bf(acc[fm][fn][r] * dv);
        }
}

// ---------------- GCN aggregation + bias + relu / softmax -------------------
// one WAVE per (node, role). Also scatter-writes transposed bf16 copies
// xe_T[128][N] and S_T[128][N] for the pooling MFMA GEMMs.
__global__ void conv_kernel(const ushort* __restrict__ h, const int* __restrict__ indptr,
                            const int* __restrict__ sorted_src, const float* __restrict__ dinv,
                            const float* __restrict__ b_emb, const float* __restrict__ b_asn,
                            float* __restrict__ S_out, uint* __restrict__ S_bf,
                            ushort* __restrict__ S_T, ushort* __restrict__ xe_T) {
    const uint* __restrict__ hp = (const uint*)h;
    int wv = threadIdx.x >> 6, lane = threadIdx.x & 63;
    int task = blockIdx.x * 4 + wv;
    int d = task >> 1, role = task & 1;
    int beg = indptr[d], end = indptr[d + 1];
    float di = dinv[d];
    int off = role * 64 + lane;
    float ax = 0.f, ay = 0.f;
    for (int ch = beg; ch < end; ch += 64) {
        int take = end - ch; if (take > 64) take = 64;
        int myi = sorted_src[ch + (lane < take ? lane : 0)];
        int i = 0;
        for (; i + 4 <= take; i += 4) {
            int s0 = __shfl(myi, i),     s1 = __shfl(myi, i + 1);
            int s2 = __shfl(myi, i + 2), s3 = __shfl(myi, i + 3);
            uint v0 = hp[(size_t)s0 * 128 + off];
            uint v1 = hp[(size_t)s1 * 128 + off];
            uint v2 = hp[(size_t)s2 * 128 + off];
            uint v3 = hp[(size_t)s3 * 128 + off];
            ax += (bflo(v0) + bflo(v1)) + (bflo(v2) + bflo(v3));
            ay += (bfhi(v0) + bfhi(v1)) + (bfhi(v2) + bfhi(v3));
        }
        for (; i < take; ++i) {
            int s = __shfl(myi, i);
            uint v = hp[(size_t)s * 128 + off];
            ax += bflo(v); ay += bfhi(v);
        }
    }
    uint vd = hp[(size_t)d * 128 + off];
    ax += bflo(vd); ay += bfhi(vd);
    ax *= di; ay *= di;
    const float2* __restrict__ bp = (const float2*)(role ? b_asn : b_emb);
    float2 bb = bp[lane];
    ax += bb.x; ay += bb.y;
    if (role == 0) {
        float ox = fmaxf(ax, 0.f), oy = fmaxf(ay, 0.f);
        xe_T[(size_t)(2 * lane) * N_NODES + d]     = f2bf(ox);
        xe_T[(size_t)(2 * lane + 1) * N_NODES + d] = f2bf(oy);
    } else {
        float m = fmaxf(ax, ay);
#pragma unroll
        for (int o2 = 32; o2; o2 >>= 1) m = fmaxf(m, __shfl_xor(m, o2));
        float e0 = __expf(ax - m), e1 = __expf(ay - m);
        float s = e0 + e1;
#pragma unroll
        for (int o2 = 32; o2; o2 >>= 1) s += __shfl_xor(s, o2);
        float inv = 1.f / s;
        float p0 = e0 * inv, p1 = e1 * inv;
        ((float2*)S_out)[(size_t)d * 64 + lane] = make_float2(p0, p1);
        S_bf[(size_t)d * 64 + lane] = pack2bf(p0, p1);
        S_T[(size_t)(2 * lane) * N_NODES + d]     = f2bf(p0);
        S_T[(size_t)(2 * lane + 1) * N_NODES + d] = f2bf(p1);
    }
}

// -------- Mt_T[i][d] = sum over UNIQUE srcs s of d of S[s, i] (bf16) --------
__global__ void mt_kernel(const uint* __restrict__ S_bf, const int* __restrict__ indptr,
                          const int* __restrict__ sorted_src, ushort* __restrict__ Mt_T) {
    __shared__ int ss[4][1024];
    int wv = threadIdx.x >> 6, lane = threadIdx.x & 63;
    int d = blockIdx.x * 4 + wv;
    int beg = indptr[d];
    int len = indptr[d + 1] - beg;
    if (len > 1024) len = 1024;
    for (int i = lane; i < len; i += 64) ss[wv][i] = sorted_src[beg + i];
    __syncthreads();
    for (int i = lane; i < len; i += 64) {
        int s = ss[wv][i];
        for (int j = 0; j < i; ++j)
            if (ss[wv][j] == s) { ss[wv][i] = -1; break; }
    }
    __syncthreads();
    float ax = 0.f, ay = 0.f;
    for (int ch = 0; ch < len; ch += 64) {
        int take = len - ch; if (take > 64) take = 64;
        int myv = ss[wv][ch + (lane < take ? lane : 0)];
        int i = 0;
        for (; i + 4 <= take; i += 4) {
            int s0 = __shfl(myv, i),     s1 = __shfl(myv, i + 1);
            int s2 = __shfl(myv, i + 2), s3 = __shfl(myv, i + 3);
            float m0 = s0 >= 0 ? 1.f : 0.f, m1 = s1 >= 0 ? 1.f : 0.f;
            float m2 = s2 >= 0 ? 1.f : 0.f, m3 = s3 >= 0 ? 1.f : 0.f;
            uint v0 = S_bf[(size_t)(s0 >= 0 ? s0 : 0) * 64 + lane];
            uint v1 = S_bf[(size_t)(s1 >= 0 ? s1 : 0) * 64 + lane];
            uint v2 = S_bf[(size_t)(s2 >= 0 ? s2 : 0) * 64 + lane];
            uint v3 = S_bf[(size_t)(s3 >= 0 ? s3 : 0) * 64 + lane];
            ax += (bflo(v0) * m0 + bflo(v1) * m1) + (bflo(v2) * m2 + bflo(v3) * m3);
            ay += (bfhi(v0) * m0 + bfhi(v1) * m1) + (bfhi(v2) * m2 + bfhi(v3) * m3);
        }
        for (; i < take; ++i) {
            int s = __shfl(myv, i);
            if (s >= 0) {
                uint v = S_bf[(size_t)s * 64 + lane];
                ax += bflo(v); ay += bfhi(v);
            }
        }
    }
    Mt_T[(size_t)(2 * lane) * N_NODES + d]     = f2bf(ax);
    Mt_T[(size_t)(2 * lane + 1) * N_NODES + d] = f2bf(ay);
}

// ---- stage 1 (MFMA): partial[g][c] = A^T_chunk @ B_chunk, chunk=128 k ------
// grid (128, 2), 512 thr (8 waves: 2m x 4n). Wave tile 64x32 over 128x128 out.
__global__ __launch_bounds__(512) void pool_stage1_mfma(
        const ushort* __restrict__ S_T, const ushort* __restrict__ xe_T,
        const ushort* __restrict__ Mt_T, float* __restrict__ part) {
    const ushort* __restrict__ A = blockIdx.y ? Mt_T : S_T;
    const ushort* __restrict__ B = blockIdx.y ? S_T : xe_T;
    float* __restrict__ out = part + (size_t)blockIdx.y * (128 * N_NODES) +
                              (size_t)blockIdx.x * 16384;
    int l = threadIdx.x & 63, w = threadIdx.x >> 6;
    int m0 = (w >> 2) * 64;
    int n0 = (w & 3) * 32;
    int lr = l & 15, lk = (l >> 4) * 8;
    int kb = blockIdx.x * 128;
    f32x4 acc[4][2] = {};
#pragma unroll
    for (int kk = 0; kk < 128; kk += 32) {
        bf16x8 a[4], b[2];
#pragma unroll
        for (int fm = 0; fm < 4; ++fm)
            a[fm] = *(const bf16x8*)(A + (size_t)(m0 + fm * 16 + lr) * N_NODES + kb + kk + lk);
#pragma unroll
        for (int fn = 0; fn < 2; ++fn)
            b[fn] = *(const bf16x8*)(B + (size_t)(n0 + fn * 16 + lr) * N_NODES + kb + kk + lk);
#pragma unroll
        for (int fm = 0; fm < 4; ++fm)
#pragma unroll
            for (int fn = 0; fn < 2; ++fn)
                acc[fm][fn] = __builtin_amdgcn_mfma_f32_16x16x32_bf16(
                    a[fm], b[fn], acc[fm][fn], 0, 0, 0);
    }
    int rbase = (l >> 4) * 4;
#pragma unroll
    for (int fm = 0; fm < 4; ++fm)
#pragma unroll
        for (int r = 0; r < 4; ++r)
#pragma unroll
            for (int fn = 0; fn < 2; ++fn)
                out[(size_t)(m0 + fm * 16 + rbase + r) * 128 + n0 + fn * 16 + lr] =
                    acc[fm][fn][r];
}

// ---- stage 2: out[idx] = sum_p partial[p][idx] -----------------------------
__global__ void pool_reduce_kernel(const float* __restrict__ part, float* __restrict__ out) {
    int idx = blockIdx.x * 256 + threadIdx.x;
    int g = idx >> 14;
    int o = idx & 16383;
    const float* __restrict__ p = part + (size_t)g * (128 * N_NODES) + o;
    float s = 0.f;
#pragma unroll 8
    for (int c = 0; c < 128; ++c) s += p[(size_t)c * 16384];
    out[idx] = s;
}

extern "C" void kernel_launch(void* const* d_in, const int* in_sizes, int n_in,
                              void* d_out, int out_size, void* d_ws, size_t ws_size,
                              hipStream_t stream) {
    const float* x      = (const float*)d_in[0];
    const int*   ei     = (const int*)d_in[1];
    const float* W_emb  = (const float*)d_in[2];
    const float* b_emb  = (const float*)d_in[3];
    const float* W_asn  = (const float*)d_in[4];
    const float* b_asn  = (const float*)d_in[5];
    const int* src = ei;
    const int* dst = ei + N_EDGES;

    float* out = (float*)d_out;
    float* S_out = out + 32768;   // outputs: x_pooled(16384), A_pooled(16384), S(N*128)

    // workspace (32 MB peak, liveness-overlapped):
    //  [0,16M): part (stage1->reduce)  overlays: x_bf[0,4M) (cvt->gemm),
    //           h[4M,12M) (gemm->conv), sorted[12M,14M) (scatter->mt),
    //           wT[14M,+64K) (cvt->gemm), smalls[14.5M..) (hist..mt)
    //  [16M,20M): S_bf  (conv->mt)
    //  [20M,24M): S_T   (conv->stage1)
    //  [24M,28M): xe_T  (conv->stage1)
    //  [28M,32M): Mt_T  (mt->stage1)
    char* ws = (char*)d_ws;
    float*  part   = (float*) (ws + 0);
    ushort* x_bf   = (ushort*)(ws + 0);
    ushort* h      = (ushort*)(ws + 4194304);
    int*    sorted = (int*)   (ws + 12582912);
    ushort* wT     = (ushort*)(ws + 14680064);
    int*    count  = (int*)   (ws + 15204352);
    int*    indptr = (int*)   (ws + 15269888);
    int*    cursor = (int*)   (ws + 15400960);
    float*  dinv   = (float*) (ws + 15466496);
    uint*   S_bf   = (uint*)  (ws + 16777216);
    ushort* S_T    = (ushort*)(ws + 20971520);
    ushort* xe_T   = (ushort*)(ws + 25165824);
    ushort* Mt_T   = (ushort*)(ws + 29360128);

    hipMemsetAsync(count, 0, 65536, stream);
    hipMemsetAsync(cursor, 0, 65536, stream);

    hist_kernel<<<2048, 256, 0, stream>>>(dst, count);
    scan_kernel<<<1, 256, 0, stream>>>(count, indptr, dinv);
    scatter_kernel<<<2048, 256, 0, stream>>>(src, dst, indptr, cursor, sorted);
    cvt_x_kernel<<<2048, 256, 0, stream>>>(x, x_bf);
    cvt_w_kernel<<<128, 256, 0, stream>>>(W_emb, W_asn, wT);
    gemm_xw_mfma<<<256, 512, 0, stream>>>(x_bf, wT, dinv, h);
    conv_kernel<<<8192, 256, 0, stream>>>(h, indptr, sorted, dinv, b_emb, b_asn,
                                          S_out, S_bf, S_T, xe_T);
    mt_kernel<<<4096, 256, 0, stream>>>(S_bf, indptr, sorted, Mt_T);
    pool_stage1_mfma<<<dim3(128, 2), 512, 0, stream>>>(S_T, xe_T, Mt_T, part);
    pool_reduce_kernel<<<128, 256, 0, stream>>>(part, out);
}

// Round 6
// 172.908 us; speedup vs baseline: 2.5981x; 1.1086x over previous
//
#include <hip/hip_runtime.h>

#define N_NODES 16384
#define N_EDGES 524288

typedef short bf16x8 __attribute__((ext_vector_type(8)));
typedef float f32x4 __attribute__((ext_vector_type(4)));

__device__ __forceinline__ ushort f2bf(float a) {
    uint u = __float_as_uint(a);
    return (ushort)((u + 0x7fff + ((u >> 16) & 1)) >> 16);
}
__device__ __forceinline__ uint pack2bf(float a, float b) {
    return (uint)f2bf(a) | ((uint)f2bf(b) << 16);
}
__device__ __forceinline__ float bflo(uint v) { return __uint_as_float(v << 16); }
__device__ __forceinline__ float bfhi(uint v) { return __uint_as_float(v & 0xffff0000u); }

// ---------------- histogram of dst ------------------------------------------
__global__ void hist_kernel(const int* __restrict__ dst, int* __restrict__ count) {
    int e = blockIdx.x * 256 + threadIdx.x;
    if (e < N_EDGES) atomicAdd(&count[dst[e]], 1);
}

// -------- exclusive scan -> indptr, plus dinv -------------------------------
__global__ void scan_kernel(const int* __restrict__ count, int* __restrict__ indptr,
                            float* __restrict__ dinv) {
    __shared__ int part[256];
    int t = threadIdx.x;
    int base = t * 64;
    int local[64];
    int s = 0;
#pragma unroll
    for (int i = 0; i < 64; ++i) { local[i] = s; s += count[base + i]; }
    part[t] = s;
    __syncthreads();
    for (int off = 1; off < 256; off <<= 1) {
        int v = (t >= off) ? part[t - off] : 0;
        __syncthreads();
        part[t] += v;
        __syncthreads();
    }
    int prefix = (t == 0) ? 0 : part[t - 1];
#pragma unroll
    for (int i = 0; i < 64; ++i) {
        indptr[base + i] = prefix + local[i];
        dinv[base + i] = rsqrtf((float)(count[base + i] + 1));
    }
    if (t == 255) indptr[N_NODES] = part[255];
}

// ---------------- counting-sort scatter -------------------------------------
__global__ void scatter_kernel(const int* __restrict__ src, const int* __restrict__ dst,
                               const int* __restrict__ indptr, int* __restrict__ cursor,
                               int* __restrict__ sorted_src) {
    int e = blockIdx.x * 256 + threadIdx.x;
    if (e < N_EDGES) {
        int d = dst[e];
        int p = indptr[d] + atomicAdd(&cursor[d], 1);
        sorted_src[p] = src[e];
    }
}

// ---------------- x -> bf16 -------------------------------------------------
__global__ void cvt_x_kernel(const float* __restrict__ x, ushort* __restrict__ x_bf) {
    int i = (blockIdx.x * 256 + threadIdx.x) * 4;
    float4 v = *(const float4*)(x + i);
    ushort4 o;
    o.x = f2bf(v.x); o.y = f2bf(v.y); o.z = f2bf(v.z); o.w = f2bf(v.w);
    *(ushort4*)(x_bf + i) = o;
}

// ---------------- pack W^T bf16: wT[n][k], n<128 emb, else asn ---------------
__global__ void cvt_w_kernel(const float* __restrict__ W_emb, const float* __restrict__ W_asn,
                             ushort* __restrict__ wT) {
    int idx = blockIdx.x * 256 + threadIdx.x;   // 32768
    int k = idx >> 8, n = idx & 255;
    float v = n < 128 ? W_emb[k * 128 + n] : W_asn[k * 128 + (n - 128)];
    wT[(size_t)n * 128 + k] = f2bf(v);
}

// ------ h[N,256](bf16) = (x_bf @ wT^T) * dinv[row] via MFMA ------------------
__global__ __launch_bounds__(512) void gemm_xw_mfma(
        const ushort* __restrict__ x_bf, const ushort* __restrict__ wT,
        const float* __restrict__ dinv, ushort* __restrict__ h) {
    int l = threadIdx.x & 63, w = threadIdx.x >> 6;
    int m0 = blockIdx.x * 64 + (w >> 2) * 32;
    int n0 = (w & 3) * 64;
    int lr = l & 15, lk = (l >> 4) * 8;
    f32x4 acc[2][4] = {};
#pragma unroll
    for (int kk = 0; kk < 128; kk += 32) {
        bf16x8 a[2], b[4];
#pragma unroll
        for (int fm = 0; fm < 2; ++fm)
            a[fm] = *(const bf16x8*)(x_bf + (size_t)(m0 + fm * 16 + lr) * 128 + kk + lk);
#pragma unroll
        for (int fn = 0; fn < 4; ++fn)
            b[fn] = *(const bf16x8*)(wT + (size_t)(n0 + fn * 16 + lr) * 128 + kk + lk);
#pragma unroll
        for (int fm = 0; fm < 2; ++fm)
#pragma unroll
            for (int fn = 0; fn < 4; ++fn)
                acc[fm][fn] = __builtin_amdgcn_mfma_f32_16x16x32_bf16(
                    a[fm], b[fn], acc[fm][fn], 0, 0, 0);
    }
    int rbase = (l >> 4) * 4;
#pragma unroll
    for (int fm = 0; fm < 2; ++fm)
#pragma unroll
        for (int r = 0; r < 4; ++r) {
            int row = m0 + fm * 16 + rbase + r;
            float dv = dinv[row];
#pragma unroll
            for (int fn = 0; fn < 4; ++fn)
                h[(size_t)row * 256 + n0 + fn * 16 + lr] = f2bf(acc[fm][fn][r] * dv);
        }
}

// ---------------- GCN aggregation + bias + relu / softmax -------------------
// one WAVE per (node, role). ALL stores coalesced row-major (packed bf16).
__global__ void conv_kernel(const ushort* __restrict__ h, const int* __restrict__ indptr,
                            const int* __restrict__ sorted_src, const float* __restrict__ dinv,
                            const float* __restrict__ b_emb, const float* __restrict__ b_asn,
                            float* __restrict__ S_out, uint* __restrict__ S_bf,
                            uint* __restrict__ xe_bf) {
    const uint* __restrict__ hp = (const uint*)h;
    int wv = threadIdx.x >> 6, lane = threadIdx.x & 63;
    int task = blockIdx.x * 4 + wv;
    int d = task >> 1, role = task & 1;
    int beg = indptr[d], end = indptr[d + 1];
    float di = dinv[d];
    int off = role * 64 + lane;
    float ax = 0.f, ay = 0.f;
    for (int ch = beg; ch < end; ch += 64) {
        int take = end - ch; if (take > 64) take = 64;
        int myi = sorted_src[ch + (lane < take ? lane : 0)];
        int i = 0;
        for (; i + 4 <= take; i += 4) {
            int s0 = __shfl(myi, i),     s1 = __shfl(myi, i + 1);
            int s2 = __shfl(myi, i + 2), s3 = __shfl(myi, i + 3);
            uint v0 = hp[(size_t)s0 * 128 + off];
            uint v1 = hp[(size_t)s1 * 128 + off];
            uint v2 = hp[(size_t)s2 * 128 + off];
            uint v3 = hp[(size_t)s3 * 128 + off];
            ax += (bflo(v0) + bflo(v1)) + (bflo(v2) + bflo(v3));
            ay += (bfhi(v0) + bfhi(v1)) + (bfhi(v2) + bfhi(v3));
        }
        for (; i < take; ++i) {
            int s = __shfl(myi, i);
            uint v = hp[(size_t)s * 128 + off];
            ax += bflo(v); ay += bfhi(v);
        }
    }
    uint vd = hp[(size_t)d * 128 + off];
    ax += bflo(vd); ay += bfhi(vd);
    ax *= di; ay *= di;
    const float2* __restrict__ bp = (const float2*)(role ? b_asn : b_emb);
    float2 bb = bp[lane];
    ax += bb.x; ay += bb.y;
    if (role == 0) {
        float ox = fmaxf(ax, 0.f), oy = fmaxf(ay, 0.f);
        xe_bf[(size_t)d * 64 + lane] = pack2bf(ox, oy);
    } else {
        float m = fmaxf(ax, ay);
#pragma unroll
        for (int o2 = 32; o2; o2 >>= 1) m = fmaxf(m, __shfl_xor(m, o2));
        float e0 = __expf(ax - m), e1 = __expf(ay - m);
        float s = e0 + e1;
#pragma unroll
        for (int o2 = 32; o2; o2 >>= 1) s += __shfl_xor(s, o2);
        float inv = 1.f / s;
        float p0 = e0 * inv, p1 = e1 * inv;
        ((float2*)S_out)[(size_t)d * 64 + lane] = make_float2(p0, p1);
        S_bf[(size_t)d * 64 + lane] = pack2bf(p0, p1);
    }
}

// -------- Mt[d][:] = sum over UNIQUE srcs s of d of S[s,:]  (packed bf16) ---
__global__ void mt_kernel(const uint* __restrict__ S_bf, const int* __restrict__ indptr,
                          const int* __restrict__ sorted_src, uint* __restrict__ Mt_bf) {
    __shared__ int ss[4][1024];
    int wv = threadIdx.x >> 6, lane = threadIdx.x & 63;
    int d = blockIdx.x * 4 + wv;
    int beg = indptr[d];
    int len = indptr[d + 1] - beg;
    if (len > 1024) len = 1024;
    for (int i = lane; i < len; i += 64) ss[wv][i] = sorted_src[beg + i];
    __syncthreads();
    for (int i = lane; i < len; i += 64) {
        int s = ss[wv][i];
        for (int j = 0; j < i; ++j)
            if (ss[wv][j] == s) { ss[wv][i] = -1; break; }
    }
    __syncthreads();
    float ax = 0.f, ay = 0.f;
    for (int ch = 0; ch < len; ch += 64) {
        int take = len - ch; if (take > 64) take = 64;
        int myv = ss[wv][ch + (lane < take ? lane : 0)];
        int i = 0;
        for (; i + 4 <= take; i += 4) {
            int s0 = __shfl(myv, i),     s1 = __shfl(myv, i + 1);
            int s2 = __shfl(myv, i + 2), s3 = __shfl(myv, i + 3);
            float m0 = s0 >= 0 ? 1.f : 0.f, m1 = s1 >= 0 ? 1.f : 0.f;
            float m2 = s2 >= 0 ? 1.f : 0.f, m3 = s3 >= 0 ? 1.f : 0.f;
            uint v0 = S_bf[(size_t)(s0 >= 0 ? s0 : 0) * 64 + lane];
            uint v1 = S_bf[(size_t)(s1 >= 0 ? s1 : 0) * 64 + lane];
            uint v2 = S_bf[(size_t)(s2 >= 0 ? s2 : 0) * 64 + lane];
            uint v3 = S_bf[(size_t)(s3 >= 0 ? s3 : 0) * 64 + lane];
            ax += (bflo(v0) * m0 + bflo(v1) * m1) + (bflo(v2) * m2 + bflo(v3) * m3);
            ay += (bfhi(v0) * m0 + bfhi(v1) * m1) + (bfhi(v2) * m2 + bfhi(v3) * m3);
        }
        for (; i < take; ++i) {
            int s = __shfl(myv, i);
            if (s >= 0) {
                uint v = S_bf[(size_t)s * 64 + lane];
                ax += bflo(v); ay += bfhi(v);
            }
        }
    }
    Mt_bf[(size_t)d * 64 + lane] = pack2bf(ax, ay);
}

// ------ LDS-tiled transpose: [16384][128] bf16 -> [128][16384] bf16 ---------
// grid (128, 3): y selects {S, xe, Mt}. 128-node x 128-ch tile per block.
__global__ __launch_bounds__(256) void transpose_kernel(
        const ushort* __restrict__ S_bf, const ushort* __restrict__ xe_bf,
        const ushort* __restrict__ Mt_bf, ushort* __restrict__ S_T,
        ushort* __restrict__ xe_T, ushort* __restrict__ Mt_T) {
    __shared__ ushort tile[128][130];
    const ushort* __restrict__ src;
    ushort* __restrict__ dst;
    if (blockIdx.y == 0)      { src = S_bf;  dst = S_T; }
    else if (blockIdx.y == 1) { src = xe_bf; dst = xe_T; }
    else                      { src = Mt_bf; dst = Mt_T; }
    int tid = threadIdx.x;
    int n0 = blockIdx.x * 128;
    for (int i = tid; i < 2048; i += 256) {        // read: 16B coalesced rows
        int r = i >> 4, c8 = (i & 15) << 3;
        const uint* p = (const uint*)(src + (size_t)(n0 + r) * 128 + c8);
        uint* t = (uint*)&tile[r][c8];
        t[0] = p[0]; t[1] = p[1]; t[2] = p[2]; t[3] = p[3];
    }
    __syncthreads();
    for (int i = tid; i < 2048; i += 256) {        // write: 16B coalesced cols
        int ch = i >> 4, n8 = (i & 15) << 3;
        ushort v[8];
#pragma unroll
        for (int j = 0; j < 8; ++j) v[j] = tile[n8 + j][ch];
        uint4 o;
        o.x = (uint)v[0] | ((uint)v[1] << 16);
        o.y = (uint)v[2] | ((uint)v[3] << 16);
        o.z = (uint)v[4] | ((uint)v[5] << 16);
        o.w = (uint)v[6] | ((uint)v[7] << 16);
        *(uint4*)(dst + (size_t)ch * N_NODES + n0 + n8) = o;
    }
}

// ---- stage 1 (MFMA): partial[g][c] = A^T_chunk @ B_chunk, chunk=128 k ------
__global__ __launch_bounds__(512) void pool_stage1_mfma(
        const ushort* __restrict__ S_T, const ushort* __restrict__ xe_T,
        const ushort* __restrict__ Mt_T, float* __restrict__ part) {
    const ushort* __restrict__ A = blockIdx.y ? Mt_T : S_T;
    const ushort* __restrict__ B = blockIdx.y ? S_T : xe_T;
    float* __restrict__ out = part + (size_t)blockIdx.y * (128 * N_NODES) +
                              (size_t)blockIdx.x * 16384;
    int l = threadIdx.x & 63, w = threadIdx.x >> 6;
    int m0 = (w >> 2) * 64;
    int n0 = (w & 3) * 32;
    int lr = l & 15, lk = (l >> 4) * 8;
    int kb = blockIdx.x * 128;
    f32x4 acc[4][2] = {};
#pragma unroll
    for (int kk = 0; kk < 128; kk += 32) {
        bf16x8 a[4], b[2];
#pragma unroll
        for (int fm = 0; fm < 4; ++fm)
            a[fm] = *(const bf16x8*)(A + (size_t)(m0 + fm * 16 + lr) * N_NODES + kb + kk + lk);
#pragma unroll
        for (int fn = 0; fn < 2; ++fn)
            b[fn] = *(const bf16x8*)(B + (size_t)(n0 + fn * 16 + lr) * N_NODES + kb + kk + lk);
#pragma unroll
        for (int fm = 0; fm < 4; ++fm)
#pragma unroll
            for (int fn = 0; fn < 2; ++fn)
                acc[fm][fn] = __builtin_amdgcn_mfma_f32_16x16x32_bf16(
                    a[fm], b[fn], acc[fm][fn], 0, 0, 0);
    }
    int rbase = (l >> 4) * 4;
#pragma unroll
    for (int fm = 0; fm < 4; ++fm)
#pragma unroll
        for (int r = 0; r < 4; ++r)
#pragma unroll
            for (int fn = 0; fn < 2; ++fn)
                out[(size_t)(m0 + fm * 16 + rbase + r) * 128 + n0 + fn * 16 + lr] =
                    acc[fm][fn][r];
}

// ---- stage 2: out[idx] = sum_p partial[p][idx] -----------------------------
__global__ void pool_reduce_kernel(const float* __restrict__ part, float* __restrict__ out) {
    int idx = blockIdx.x * 256 + threadIdx.x;
    int g = idx >> 14;
    int o = idx & 16383;
    const float* __restrict__ p = part + (size_t)g * (128 * N_NODES) + o;
    float s = 0.f;
#pragma unroll 8
    for (int c = 0; c < 128; ++c) s += p[(size_t)c * 16384];
    out[idx] = s;
}

extern "C" void kernel_launch(void* const* d_in, const int* in_sizes, int n_in,
                              void* d_out, int out_size, void* d_ws, size_t ws_size,
                              hipStream_t stream) {
    const float* x      = (const float*)d_in[0];
    const int*   ei     = (const int*)d_in[1];
    const float* W_emb  = (const float*)d_in[2];
    const float* b_emb  = (const float*)d_in[3];
    const float* W_asn  = (const float*)d_in[4];
    const float* b_asn  = (const float*)d_in[5];
    const int* src = ei;
    const int* dst = ei + N_EDGES;

    float* out = (float*)d_out;
    float* S_out = out + 32768;   // outputs: x_pooled(16384), A_pooled(16384), S(N*128)

    // workspace (32 MB peak, liveness-overlapped):
    //  [0,4M)   x_bf (cvt->gemm), then Mt_T (transpose->stage1)
    //  [4M,12M) h (gemm->conv), then S_T[4,8M) + xe_T[8,12M) (transpose->stage1)
    //  [12,14M) sorted (scatter->mt)
    //  [14M,..) wT + smalls
    //  [16,20M) S_bf (conv->transpose), [20,24M) xe_bf, [24,28M) Mt_bf
    //  [16,32M) part (stage1->reduce; S_bf/xe_bf/Mt_bf dead)
    char* ws = (char*)d_ws;
    ushort* x_bf   = (ushort*)(ws + 0);
    ushort* Mt_T   = (ushort*)(ws + 0);
    ushort* h      = (ushort*)(ws + 4194304);
    ushort* S_T    = (ushort*)(ws + 4194304);
    ushort* xe_T   = (ushort*)(ws + 8388608);
    int*    sorted = (int*)   (ws + 12582912);
    ushort* wT     = (ushort*)(ws + 14680064);
    int*    count  = (int*)   (ws + 15204352);
    int*    indptr = (int*)   (ws + 15269888);
    int*    cursor = (int*)   (ws + 15400960);
    float*  dinv   = (float*) (ws + 15466496);
    uint*   S_bf   = (uint*)  (ws + 16777216);
    uint*   xe_bf  = (uint*)  (ws + 20971520);
    uint*   Mt_bf  = (uint*)  (ws + 25165824);
    float*  part   = (float*) (ws + 16777216);

    hipMemsetAsync(count, 0, 65536, stream);
    hipMemsetAsync(cursor, 0, 65536, stream);

    hist_kernel<<<2048, 256, 0, stream>>>(dst, count);
    scan_kernel<<<1, 256, 0, stream>>>(count, indptr, dinv);
    scatter_kernel<<<2048, 256, 0, stream>>>(src, dst, indptr, cursor, sorted);
    cvt_x_kernel<<<2048, 256, 0, stream>>>(x, x_bf);
    cvt_w_kernel<<<128, 256, 0, stream>>>(W_emb, W_asn, wT);
    gemm_xw_mfma<<<256, 512, 0, stream>>>(x_bf, wT, dinv, h);
    conv_kernel<<<8192, 256, 0, stream>>>(h, indptr, sorted, dinv, b_emb, b_asn,
                                          S_out, S_bf, xe_bf);
    mt_kernel<<<4096, 256, 0, stream>>>(S_bf, indptr, sorted, Mt_bf);
    transpose_kernel<<<dim3(128, 3), 256, 0, stream>>>(
        (const ushort*)S_bf, (const ushort*)xe_bf, (const ushort*)Mt_bf, S_T, xe_T, Mt_T);
    pool_stage1_mfma<<<dim3(128, 2), 512, 0, stream>>>(S_T, xe_T, Mt_T, part);
    pool_reduce_kernel<<<128, 256, 0, stream>>>(part, out);
}